// Round 2
// baseline (58.330 us; speedup 1.0000x reference)
//
#include <hip/hip_runtime.h>
#include <math.h>

// Problem constants
#define Bq 64
#define Nq 256
#define Dq 512
#define Vq 50257
#define Kq 100
#define KP 112              // K padded to 7*16
#define NKT 7               // k-tiles of 16
#define NDT_W 4             // d-tiles of 32 per wave (D split 4 ways: 128 floats/wave)
#define NORM_TERM 10.8249051f   // log(50257)
#define LOGK 4.6051702f         // log(100)
#define NBLK 1024           // 16384 positions / 16 per block

typedef __attribute__((ext_vector_type(8))) short short8;
typedef __attribute__((ext_vector_type(4))) float floatx4;
typedef __attribute__((ext_vector_type(4))) unsigned short ushort4v;

__device__ __forceinline__ unsigned short f2bf(float f) {
    union { float f; unsigned u; } v; v.f = f;
    unsigned r = v.u + 0x7FFFu + ((v.u >> 16) & 1u);   // RNE
    return (unsigned short)(r >> 16);
}

__device__ __forceinline__ float dot4(floatx4 a, floatx4 b) {
    return a.x*b.x + a.y*b.y + a.z*b.z + a.w*b.w;
}

__device__ __forceinline__ float log_sigmoid(float x) {
    // log(sigmoid(x)) = min(x,0) - log1p(exp(-|x|))
    return fminf(x, 0.f) - log1pf(expf(-fabsf(x)));
}

// Gather + convert noise embedding rows to bf16 [112][512], zero-padded.
// Also precompute per-noise adjustment and zero the completion counter.
__global__ void prep_noise(const float* __restrict__ emb_w,
                           const float* __restrict__ emb_b,
                           const float* __restrict__ lpn,
                           const int* __restrict__ ns,
                           unsigned short* __restrict__ nB,
                           float* __restrict__ nAdj,
                           unsigned* __restrict__ counter) {
    int k = blockIdx.x;     // 0..111
    int t = threadIdx.x;    // 0..63
    if (k == 0 && t == 0) *counter = 0u;
    if (k < Kq) {
        int row = ns[k];
        const floatx4* src = (const floatx4*)(emb_w + (size_t)row * Dq);
        ushort4v* dst = (ushort4v*)(nB + (size_t)k * Dq);
#pragma unroll
        for (int i = 0; i < 2; ++i) {
            floatx4 v = src[t + i * 64];
            ushort4v o;
            o.x = f2bf(v.x); o.y = f2bf(v.y); o.z = f2bf(v.z); o.w = f2bf(v.w);
            dst[t + i * 64] = o;
        }
        if (t == 0) nAdj[k] = emb_b[row] - NORM_TERM - lpn[row] - LOGK;
    } else {
        ushort4v* dst = (ushort4v*)(nB + (size_t)k * Dq);
        ushort4v z; z.x = 0; z.y = 0; z.z = 0; z.w = 0;
        dst[t] = z; dst[t + 64] = z;
        if (t == 0) nAdj[k] = 0.f;
    }
}

// Block = 4 waves = 16 positions; wave w owns d-range [w*128, w*128+128).
// Per wave: fp32 target-dot partial + bf16 A-frags from ONE read of its
// input slice; 7 k-tiles of noise MFMA. Cross-wave reduce via LDS, parallel
// epilogue, last-block final reduction (atomic ticket).
__global__ __launch_bounds__(256, 4) void nce_main(
    const float* __restrict__ input,     // [16384][512]
    const float* __restrict__ emb_w,     // [V][512]
    const float* __restrict__ emb_b,     // [V]
    const float* __restrict__ lpn,       // [V]
    const int* __restrict__ target,      // [16384]
    const unsigned short* __restrict__ nB,   // [112][512] bf16
    const float* __restrict__ nAdj,          // [112]
    float* __restrict__ partials,            // [1024]
    unsigned* __restrict__ counter,
    float* __restrict__ out)                 // [64]
{
    __shared__ float red[4][64][33];   // [wave][lane][28 acc + 1 acc_t], padded
    __shared__ float blocksum[4];
    __shared__ int last_flag;

    int tid  = threadIdx.x;
    int lane = tid & 63;
    int w    = tid >> 6;            // wave id in block = D-slice id
    int pos0 = (int)blockIdx.x * 16;
    int r16  = lane & 15;           // A row (position) / B col (noise idx)
    int g4   = lane >> 4;           // k-group within d-tile

    int mypos = pos0 + r16;
    int tgt   = target[mypos];
    const float* inrow = input + (size_t)mypos * Dq;
    const float* trow  = emb_w + (size_t)tgt  * Dq;

    // Load this wave's D-slice of input once: fp32 target dot + bf16 A frags.
    short8 afrag[NDT_W];
    float acc_t = 0.f;
#pragma unroll
    for (int dt = 0; dt < NDT_W; ++dt) {
        int d0 = w * 128 + dt * 32 + g4 * 8;
        floatx4 x0 = *(const floatx4*)(inrow + d0);
        floatx4 x1 = *(const floatx4*)(inrow + d0 + 4);
        floatx4 t0 = *(const floatx4*)(trow + d0);
        floatx4 t1 = *(const floatx4*)(trow + d0 + 4);
        acc_t += dot4(x0, t0) + dot4(x1, t1);
        short8 a;
        a[0] = (short)f2bf(x0.x); a[1] = (short)f2bf(x0.y);
        a[2] = (short)f2bf(x0.z); a[3] = (short)f2bf(x0.w);
        a[4] = (short)f2bf(x1.x); a[5] = (short)f2bf(x1.y);
        a[6] = (short)f2bf(x1.z); a[7] = (short)f2bf(x1.w);
        afrag[dt] = a;
    }
    // sum partial target dot over the 4 k-groups (lanes r16+{0,16,32,48})
    acc_t += __shfl_xor(acc_t, 16);
    acc_t += __shfl_xor(acc_t, 32);

    floatx4 acc[NKT];
#pragma unroll
    for (int kt = 0; kt < NKT; ++kt) {
        acc[kt].x = 0.f; acc[kt].y = 0.f; acc[kt].z = 0.f; acc[kt].w = 0.f;
    }

#pragma unroll
    for (int kt = 0; kt < NKT; ++kt) {
        const unsigned short* brow = nB + (size_t)(kt * 16 + r16) * Dq;
#pragma unroll
        for (int dt = 0; dt < NDT_W; ++dt) {
            short8 bfr = *(const short8*)(brow + w * 128 + dt * 32 + g4 * 8);
            acc[kt] = __builtin_amdgcn_mfma_f32_16x16x32_bf16(
                afrag[dt], bfr, acc[kt], 0, 0, 0);
        }
    }

    // Cross-wave reduction: each wave writes its 28 acc values + acc_t.
#pragma unroll
    for (int kt = 0; kt < NKT; ++kt) {
#pragma unroll
        for (int r = 0; r < 4; ++r) red[w][lane][kt * 4 + r] = acc[kt][r];
    }
    red[w][lane][28] = acc_t;
    __syncthreads();

    // Parallel epilogue: wave 0:{kt0,1} 1:{kt2,3} 2:{kt4,5} 3:{kt6 + target}.
    // D mapping: col(noise-in-tile)=r16, row(position-in-tile)=g4*4+r.
    float contrib = 0.f;
    int ktbeg = w * 2;
    int ktend = (w == 3) ? 7 : ktbeg + 2;
    for (int kt = ktbeg; kt < ktend; ++kt) {
        int k = kt * 16 + r16;
        if (k < Kq) {
            float adj = nAdj[k];
#pragma unroll
            for (int r = 0; r < 4; ++r) {
                int j = kt * 4 + r;
                float s = red[0][lane][j] + red[1][lane][j]
                        + red[2][lane][j] + red[3][lane][j];
                contrib += log_sigmoid(-(s + adj));
            }
        }
    }
    if (w == 3 && g4 == 0) {   // lanes 0..15: one position each
        float at = red[0][lane][28] + red[1][lane][28]
                 + red[2][lane][28] + red[3][lane][28];
        float xt = at + emb_b[tgt] - NORM_TERM - lpn[tgt] - LOGK;
        contrib += log_sigmoid(xt);
    }
#pragma unroll
    for (int off = 32; off >= 1; off >>= 1)
        contrib += __shfl_xor(contrib, off);
    if (lane == 0) blocksum[w] = contrib;
    __syncthreads();

    // Block partial + last-block-done final reduction (deterministic order).
    if (tid == 0) {
        partials[blockIdx.x] = blocksum[0] + blocksum[1] + blocksum[2] + blocksum[3];
        __threadfence();
        unsigned t = atomicAdd(counter, 1u);
        last_flag = (t == NBLK - 1);
    }
    __syncthreads();
    if (last_flag && tid < 64) {
        __threadfence();
        const volatile float* p = (const volatile float*)partials;
        float s = 0.f;
        for (int i = 0; i < 16; ++i) s += p[tid * 16 + i];
        out[tid] = s;
    }
}

extern "C" void kernel_launch(void* const* d_in, const int* in_sizes, int n_in,
                              void* d_out, int out_size, void* d_ws, size_t ws_size,
                              hipStream_t stream) {
    const float* input = (const float*)d_in[0];
    const float* emb_w = (const float*)d_in[1];
    const float* emb_b = (const float*)d_in[2];
    const float* lpn   = (const float*)d_in[3];
    const int*   tgt   = (const int*)d_in[4];
    const int*   ns    = (const int*)d_in[5];
    float* out = (float*)d_out;

    // ws layout: [0,114688) noise bf16; then nAdj (448B pad to 512);
    // then partials (4096B); then counter.
    unsigned short* nB  = (unsigned short*)d_ws;
    float* nAdj     = (float*)((char*)d_ws + (size_t)KP * Dq * 2);
    float* partials = (float*)((char*)d_ws + (size_t)KP * Dq * 2 + 512);
    unsigned* counter = (unsigned*)((char*)d_ws + (size_t)KP * Dq * 2 + 512 + 4096);

    prep_noise<<<KP, 64, 0, stream>>>(emb_w, emb_b, lpn, ns, nB, nAdj, counter);
    nce_main<<<NBLK, 256, 0, stream>>>(input, emb_w, emb_b, lpn, tgt, nB, nAdj,
                                       partials, counter, out);
}

// Round 3
// 33.531 us; speedup vs baseline: 1.7396x; 1.7396x over previous
//
#include <hip/hip_runtime.h>
#include <math.h>

// Problem constants
#define Dq 512
#define Vq 50257
#define Kq 100
#define KP 112              // K padded to 7*16
#define NORM_TERM 10.8249051f   // log(50257)
#define LOGK 4.6051702f         // log(100)
#define NBLK 1024           // 16384 positions / 16 per block

typedef __attribute__((ext_vector_type(8))) short short8;
typedef __attribute__((ext_vector_type(4))) float floatx4;
typedef __attribute__((ext_vector_type(4))) unsigned short ushort4v;

__device__ __forceinline__ unsigned short f2bf(float f) {
    union { float f; unsigned u; } v; v.f = f;
    unsigned r = v.u + 0x7FFFu + ((v.u >> 16) & 1u);   // RNE
    return (unsigned short)(r >> 16);
}

__device__ __forceinline__ float log_sigmoid(float x) {
    // log(sigmoid(x)) = min(x,0) - log(1 + exp(-|x|)); fast-math variants OK
    return fminf(x, 0.f) - __logf(1.f + __expf(-fabsf(x)));
}

// Gather + convert noise embedding rows to bf16 [112][512], zero-padded.
// Also precompute per-noise adjustment: bias - NORM - logprob_noise - logK.
__global__ void prep_noise(const float* __restrict__ emb_w,
                           const float* __restrict__ emb_b,
                           const float* __restrict__ lpn,
                           const int* __restrict__ ns,
                           unsigned short* __restrict__ nB,
                           float* __restrict__ nAdj) {
    int k = blockIdx.x;     // 0..111
    int t = threadIdx.x;    // 0..63
    if (k < Kq) {
        int row = ns[k];
        const floatx4* src = (const floatx4*)(emb_w + (size_t)row * Dq);
        ushort4v* dst = (ushort4v*)(nB + (size_t)k * Dq);
#pragma unroll
        for (int i = 0; i < 2; ++i) {
            floatx4 v = src[t + i * 64];
            ushort4v o;
            o.x = f2bf(v.x); o.y = f2bf(v.y); o.z = f2bf(v.z); o.w = f2bf(v.w);
            dst[t + i * 64] = o;
        }
        if (t == 0) nAdj[k] = emb_b[row] - NORM_TERM - lpn[row] - LOGK;
    } else {
        ushort4v* dst = (ushort4v*)(nB + (size_t)k * Dq);
        ushort4v z; z.x = 0; z.y = 0; z.z = 0; z.w = 0;
        dst[t] = z; dst[t + 64] = z;
        if (t == 0) nAdj[k] = 0.f;
    }
}

// Block = 4 waves = 16 positions (same batch). Stage 16 input rows once in
// LDS (bf16, XOR-swizzled). Wave w owns k-tiles {2w, 2w+1}; wave 3 owns
// k-tile 6 + the target tile (diag of X·T^T via MFMA). Full-D accumulators
// per wave -> NO cross-wave reduction, no fence, wave-local epilogue.
__global__ __launch_bounds__(256, 8) void nce_main(
    const float* __restrict__ input,     // [16384][512]
    const float* __restrict__ emb_w,     // [V][512]
    const float* __restrict__ emb_b,     // [V]
    const float* __restrict__ lpn,       // [V]
    const int* __restrict__ target,      // [16384]
    const unsigned short* __restrict__ nB,   // [112][512] bf16
    const float* __restrict__ nAdj,          // [112]
    float* __restrict__ partials)            // [1024]
{
    // A_lds: bf16 [16][512], byte offset = row*1024 + (col*2 ^ ((row&7)<<4))
    __shared__ unsigned short A_lds[16 * 512];
    __shared__ float blocksum[4];

    int tid  = threadIdx.x;
    int lane = tid & 63;
    int w    = tid >> 6;            // wave id = k-tile group
    int pos0 = (int)blockIdx.x * 16;
    int r16  = lane & 15;
    int g4   = lane >> 4;

    // ---- Stage 16 input rows -> LDS bf16 (each wave: 4 rows) ----
    {
        int row = w * 4 + g4;                 // 0..15
        const float* src = input + (size_t)(pos0 + row) * Dq;
        char* base = (char*)A_lds + row * 1024;
        int sw = (row & 7) << 4;
#pragma unroll
        for (int j = 0; j < 8; ++j) {
            int c = r16 * 4 + j * 64;         // float col
            floatx4 v = *(const floatx4*)(src + c);
            ushort4v o;
            o.x = f2bf(v.x); o.y = f2bf(v.y); o.z = f2bf(v.z); o.w = f2bf(v.w);
            *(ushort4v*)(base + ((c * 2) ^ sw)) = o;
        }
    }
    __syncthreads();

    // A-frag for d-tile dt: row r16, k-chunk g4*8 (16B ds_read, swizzled)
    const char* abase = (const char*)A_lds + r16 * 1024;
    int asw = (r16 & 7) << 4;

    float contrib = 0.f;

    if (w < 3) {
        // two k-tiles, shared A-read per dt (1 ds_read feeds 2 MFMAs)
        const unsigned short* b0 = nB + (size_t)(w * 2 * 16 + r16) * Dq + g4 * 8;
        const unsigned short* b1 = b0 + 16 * Dq;
        floatx4 acc0 = {0.f, 0.f, 0.f, 0.f};
        floatx4 acc1 = {0.f, 0.f, 0.f, 0.f};
#pragma unroll
        for (int dt = 0; dt < 16; ++dt) {
            short8 a = *(const short8*)(abase + (((dt * 64) + g4 * 16) ^ asw));
            short8 f0 = *(const short8*)(b0 + dt * 32);
            short8 f1 = *(const short8*)(b1 + dt * 32);
            acc0 = __builtin_amdgcn_mfma_f32_16x16x32_bf16(a, f0, acc0, 0, 0, 0);
            acc1 = __builtin_amdgcn_mfma_f32_16x16x32_bf16(a, f1, acc1, 0, 0, 0);
        }
        // D mapping: col(noise-in-tile)=r16, row(position)=g4*4+r; sum rows.
        float adj0 = nAdj[w * 32 + r16];
        float adj1 = nAdj[w * 32 + 16 + r16];
#pragma unroll
        for (int r = 0; r < 4; ++r) {
            contrib += log_sigmoid(-(acc0[r] + adj0));
            contrib += log_sigmoid(-(acc1[r] + adj1));
        }
    } else {
        // k-tile 6 (k=96..111, valid k<100) + target-diag tile
        int tgt = target[pos0 + r16];
        const unsigned short* b6 = nB + (size_t)(96 + r16) * Dq + g4 * 8;
        const float* trow = emb_w + (size_t)tgt * Dq + g4 * 8;
        floatx4 acc6 = {0.f, 0.f, 0.f, 0.f};
        floatx4 accT = {0.f, 0.f, 0.f, 0.f};
#pragma unroll
        for (int dt = 0; dt < 16; ++dt) {
            short8 a = *(const short8*)(abase + (((dt * 64) + g4 * 16) ^ asw));
            short8 f6 = *(const short8*)(b6 + dt * 32);
            floatx4 t0 = *(const floatx4*)(trow + dt * 32);
            floatx4 t1 = *(const floatx4*)(trow + dt * 32 + 4);
            short8 ft;
            ft[0] = (short)f2bf(t0.x); ft[1] = (short)f2bf(t0.y);
            ft[2] = (short)f2bf(t0.z); ft[3] = (short)f2bf(t0.w);
            ft[4] = (short)f2bf(t1.x); ft[5] = (short)f2bf(t1.y);
            ft[6] = (short)f2bf(t1.z); ft[7] = (short)f2bf(t1.w);
            acc6 = __builtin_amdgcn_mfma_f32_16x16x32_bf16(a, f6, acc6, 0, 0, 0);
            accT = __builtin_amdgcn_mfma_f32_16x16x32_bf16(a, ft, accT, 0, 0, 0);
        }
        if (96 + r16 < Kq) {
            float adj6 = nAdj[96 + r16];
#pragma unroll
            for (int r = 0; r < 4; ++r)
                contrib += log_sigmoid(-(acc6[r] + adj6));
        }
        // diag of target tile: lane holds D[g4*4+r][r16]; diag when g4==r16>>2
        if ((r16 >> 2) == g4) {
            float xt = accT[r16 & 3] + emb_b[tgt] - NORM_TERM - lpn[tgt] - LOGK;
            contrib += log_sigmoid(xt);
        }
    }

#pragma unroll
    for (int off = 32; off >= 1; off >>= 1)
        contrib += __shfl_xor(contrib, off);
    if (lane == 0) blocksum[w] = contrib;
    __syncthreads();
    if (tid == 0)
        partials[blockIdx.x] = blocksum[0] + blocksum[1] + blocksum[2] + blocksum[3];
}

// Deterministic per-batch reduction: out[b] = sum of 16 block partials.
__global__ void finalize(const float* __restrict__ partials,
                         float* __restrict__ out) {
    int b = threadIdx.x;  // 0..63
    float s = 0.f;
    for (int i = 0; i < 16; ++i) s += partials[b * 16 + i];
    out[b] = s;
}

extern "C" void kernel_launch(void* const* d_in, const int* in_sizes, int n_in,
                              void* d_out, int out_size, void* d_ws, size_t ws_size,
                              hipStream_t stream) {
    const float* input = (const float*)d_in[0];
    const float* emb_w = (const float*)d_in[1];
    const float* emb_b = (const float*)d_in[2];
    const float* lpn   = (const float*)d_in[3];
    const int*   tgt   = (const int*)d_in[4];
    const int*   ns    = (const int*)d_in[5];
    float* out = (float*)d_out;

    // ws layout: [0,114688) noise bf16; [114688,115200) nAdj(+pad);
    // [115200,119296) partials.
    unsigned short* nB  = (unsigned short*)d_ws;
    float* nAdj     = (float*)((char*)d_ws + (size_t)KP * Dq * 2);
    float* partials = (float*)((char*)d_ws + (size_t)KP * Dq * 2 + 512);

    prep_noise<<<KP, 64, 0, stream>>>(emb_w, emb_b, lpn, ns, nB, nAdj);
    nce_main<<<NBLK, 256, 0, stream>>>(input, emb_w, emb_b, lpn, tgt, nB, nAdj,
                                       partials);
    finalize<<<1, 64, 0, stream>>>(partials, out);
}